// Round 11
// baseline (226.289 us; speedup 1.0000x reference)
//
#include <hip/hip_runtime.h>
#include <math.h>

// Problem constants (b=8, c=2048, e=64, h=8)
#define NTOK 16384
#define EDIM 64
#define HHE  512   // h*e

typedef _Float16 half8 __attribute__((ext_vector_type(8)));   // MFMA operand type
typedef __fp16   half2v __attribute__((ext_vector_type(2)));  // builtin V2h type
typedef float    floatx4 __attribute__((ext_vector_type(4)));

__device__ __forceinline__ half8 cvt8(const float4 a, const float4 b) {
    half8 h;
    h[0] = (_Float16)a.x; h[1] = (_Float16)a.y;
    h[2] = (_Float16)a.z; h[3] = (_Float16)a.w;
    h[4] = (_Float16)b.x; h[5] = (_Float16)b.y;
    h[6] = (_Float16)b.z; h[7] = (_Float16)b.w;
    return h;
}

// fp32 += half2 . half2 (v_dot2_f32_f16); float fallback if builtin missing
__device__ __forceinline__ float dot2(half2v a, half2v b, float c) {
#if __has_builtin(__builtin_amdgcn_fdot2)
    return __builtin_amdgcn_fdot2(a, b, c, false);
#else
    return fmaf((float)a[0], (float)b[0], fmaf((float)a[1], (float)b[1], c));
#endif
}
__device__ __forceinline__ half2v pk(float x, float y) {
    return __builtin_amdgcn_cvt_pkrtz(x, y);   // v_cvt_pkrtz_f16_f32 (V2h)
}

// ---------------------------------------------------------------------------
// Kernel 1: q/k/v = x @ W^T + b   (M=16384, N=512 per matrix, K=64) — MFMA
// R10 change: OPERANDS SWAPPED (af = W-frag, bf = x-frag). R7's working code
// proves D[row][col] = sum_k A[row][k]*B[col][k] with row=(quad,reg),
// col=lane&15. Swapped: lane&15 = token, (quad*4+reg) = column -> each lane
// holds 4 CONSECUTIVE columns of one token -> epilogue is 8 dwordx4 stores
// per thread (was 32 scalar dwords). Bytes & numerics identical; tests
// store-issue-bound vs HBM-write-bound for qkv's 1.79 TB/s plateau.
// ---------------------------------------------------------------------------
__global__ __launch_bounds__(256) void qkv_kernel(
    const float* __restrict__ x,
    const float* __restrict__ Wk, const float* __restrict__ bk,
    const float* __restrict__ Wq, const float* __restrict__ bq,
    const float* __restrict__ Wv, const float* __restrict__ bv,
    float* __restrict__ qb, float* __restrict__ kb, float* __restrict__ vb)
{
    const int tid  = threadIdx.x;
    const int lane = tid & 63;
    const int wv   = tid >> 6;             // wave 0..3
    const int z    = blockIdx.z;

    const float* W; const float* bias; float* outp;
    if      (z == 0) { W = Wk; bias = bk; outp = kb; }
    else if (z == 1) { W = Wq; bias = bq; outp = qb; }
    else             { W = Wv; bias = bv; outp = vb; }

    const int tok0 = blockIdx.x * 64 + wv * 16;   // this wave's 16 tokens
    const int col0 = blockIdx.y * 128;            // this block's 128 cols

    const int m    = lane & 15;            // B row (tok) after swap / A row (col)
    const int quad = lane >> 4;            // k-quad: k = quad*8 + j

    floatx4 acc[8];
    #pragma unroll
    for (int ct = 0; ct < 8; ++ct) acc[ct] = (floatx4){0.f, 0.f, 0.f, 0.f};

    const float* xrow = x + (size_t)(tok0 + m) * EDIM + quad * 8;

    #pragma unroll
    for (int kc = 0; kc < 2; ++kc) {       // K=64 in two 32-chunks
        const float4 xa = *(const float4*)(xrow + kc * 32);
        const float4 xb = *(const float4*)(xrow + kc * 32 + 4);
        const half8 bf = cvt8(xa, xb);     // x is now the B operand
        #pragma unroll
        for (int ct = 0; ct < 8; ++ct) {
            const float* wrow =
                W + (size_t)(col0 + ct * 16 + m) * EDIM + quad * 8 + kc * 32;
            const float4 wa = *(const float4*)(wrow);
            const float4 wb = *(const float4*)(wrow + 4);
            const half8 af = cvt8(wa, wb); // W is now the A operand
            acc[ct] = __builtin_amdgcn_mfma_f32_16x16x32_f16(af, bf, acc[ct], 0, 0, 0);
        }
    }

    // epilogue: D row = col (quad*4+reg), D col = tok (m) -> float4 store of
    // 4 consecutive columns for this lane's token.
    const int tok = tok0 + m;
    #pragma unroll
    for (int ct = 0; ct < 8; ++ct) {
        const int col = col0 + ct * 16 + quad * 4;
        const float4 b4 = *(const float4*)&bias[col];
        float4 o;
        o.x = acc[ct][0] + b4.x;
        o.y = acc[ct][1] + b4.y;
        o.z = acc[ct][2] + b4.z;
        o.w = acc[ct][3] + b4.w;
        *(float4*)&outp[(size_t)tok * HHE + col] = o;
    }
}

// ---------------------------------------------------------------------------
// Kernel 2: per-token scores -> entmax_bisect -> att @ v  — fp16 LDS + dot2
// R10 version, unchanged. Held constant.
// ---------------------------------------------------------------------------
__device__ __forceinline__ float clamp01(float z) {
    return __builtin_amdgcn_fmed3f(z, 0.0f, 1.0f);   // v_med3_f32
}
__device__ __forceinline__ float pgen(float z, float inv) {
    return z > 0.0f ? exp2f(inv * log2f(fmaxf(z, 1e-30f))) : 0.0f;
}

__global__ __launch_bounds__(256) void attn_kernel(
    float* qb,                    // read q, then write res (alias)
    const float* __restrict__ kb, const float* __restrict__ vb,
    const float* alpha_p)
{
    // per-wave private slices (1 KB each): no cross-wave sharing, no barrier
    __shared__ __align__(16) half2v kT[4][64 * 4];   // [w][j*4 + hpair]
    __shared__ __align__(16) half2v v16[4][8 * 32];  // [w][h*32 + jpair]

    const int lane = threadIdx.x & 63;
    const int w    = threadIdx.x >> 6;
    const int tok  = blockIdx.x * 4 + w;

    const float alpha = alpha_p[0];
    const float am1   = alpha - 1.0f;

    const float* __restrict__ qp = qb + (size_t)tok * HHE;
    const float* __restrict__ kp = kb + (size_t)tok * HHE;
    const float* __restrict__ vp = vb + (size_t)tok * HHE;

    // ---- load q (per-lane), stage k transposed + v packed (coalesced)
    float qr[8];
    #pragma unroll
    for (int h = 0; h < 8; ++h) qr[h] = qp[h * 64 + lane];
    half2v q2[4];
    #pragma unroll
    for (int i = 0; i < 4; ++i) q2[i] = pk(qr[2 * i], qr[2 * i + 1]);

    {   // k: lane j=lane reads k[h][j] for all h, packs h-pairs, one b128 write
        float kv[8];
        #pragma unroll
        for (int h = 0; h < 8; ++h) kv[h] = kp[h * 64 + lane];
        union { half8 h8; half2v h2[4]; } u;
        #pragma unroll
        for (int i = 0; i < 4; ++i) u.h2[i] = pk(kv[2 * i], kv[2 * i + 1]);
        *(half8*)&kT[w][lane * 4] = u.h8;
    }
    {   // v: lane (jp = lane&31, hh = lane>>5) stages 4 h rows of j-pair jp
        const int jp = lane & 31;
        const int hh = lane >> 5;
        #pragma unroll
        for (int hi = 0; hi < 4; ++hi) {
            const int h = hh * 4 + hi;
            const float2 vv = *(const float2*)&vp[h * 64 + 2 * jp];
            v16[w][h * 32 + jp] = pk(vv.x, vv.y);
        }
    }
    // wave-private LDS: compiler's lgkmcnt ordering suffices (no barrier)

    // ---- dot row: row[j] = sum_h q[h][lane] * k[h][j]  (4 dot2 per j)
    float row[64];
    #pragma unroll
    for (int j = 0; j < 64; ++j) {
        union { half8 h8; half2v h2[4]; } u;
        u.h8 = *(const half8*)&kT[w][j * 4];        // broadcast b128
        float d = dot2(q2[0], u.h2[0], 0.0f);
        d = dot2(q2[1], u.h2[1], d);
        d = dot2(q2[2], u.h2[2], d);
        d = dot2(q2[3], u.h2[3], d);
        row[j] = d;
    }

    // Xa = dot/sqrt(e) * (alpha-1);  1/8 and am1 fold exactly (pow-of-2)
    const float scale = am1 * 0.125f;
    #pragma unroll
    for (int j = 0; j < 64; ++j) row[j] *= scale;

    float mx = row[0];
    #pragma unroll
    for (int j = 1; j < 64; ++j) mx = fmaxf(mx, row[j]);

    float tau_lo = mx - 1.0f;                         // _gp(1, alpha) = 1
    const float tau_hi = mx - exp2f(-6.0f * am1);     // (1/64)^am1
    float dm = tau_hi - tau_lo;
    float inv_sum;

    if (am1 == 0.5f) {
        // alpha = 1.5: p(z) = max(z,0)^2; z <= 1 always (tau >= mx-1).
        // 6 bisection steps, f >= 0 test (f_lo >= 0 provably; one-hot-safe).
        #pragma unroll
        for (int it = 0; it < 6; ++it) {
            dm *= 0.5f;
            const float tau_m = tau_lo + dm;
            float f0 = -1.0f, f1 = 0.0f, f2 = 0.0f, f3 = 0.0f;
            #pragma unroll
            for (int j = 0; j < 64; j += 4) {
                const float a0 = clamp01(row[j+0] - tau_m);
                const float a1 = clamp01(row[j+1] - tau_m);
                const float a2 = clamp01(row[j+2] - tau_m);
                const float a3 = clamp01(row[j+3] - tau_m);
                f0 = fmaf(a0, a0, f0); f1 = fmaf(a1, a1, f1);
                f2 = fmaf(a2, a2, f2); f3 = fmaf(a3, a3, f3);
            }
            const float f = (f0 + f1) + (f2 + f3);
            tau_lo = (f >= 0.0f) ? tau_m : tau_lo;
        }
        // 3 guarded Newton steps (tau += max(f,0)/(2s); never moves if f<0)
        float tau = tau_lo;
        #pragma unroll
        for (int it = 0; it < 3; ++it) {
            float f0 = -1.0f, f1 = 0.0f, f2 = 0.0f, f3 = 0.0f;
            float s0 = 0.0f, s1 = 0.0f, s2 = 0.0f, s3 = 0.0f;
            #pragma unroll
            for (int j = 0; j < 64; j += 4) {
                const float a0 = clamp01(row[j+0] - tau);
                const float a1 = clamp01(row[j+1] - tau);
                const float a2 = clamp01(row[j+2] - tau);
                const float a3 = clamp01(row[j+3] - tau);
                f0 = fmaf(a0, a0, f0); f1 = fmaf(a1, a1, f1);
                f2 = fmaf(a2, a2, f2); f3 = fmaf(a3, a3, f3);
                s0 += a0; s1 += a1; s2 += a2; s3 += a3;
            }
            const float f = (f0 + f1) + (f2 + f3);
            const float s = ((s0 + s1) + (s2 + s3)) + 1e-20f;  // s >= 1/8 anyway
            tau = tau + fmaxf(f, 0.0f) / (s + s);
        }
        // final p (unnormalized) + sum; normalization folded into av epilogue
        float s0 = 0.0f, s1 = 0.0f;
        #pragma unroll
        for (int j = 0; j < 64; j += 2) {
            float a0 = clamp01(row[j+0] - tau);
            float a1 = clamp01(row[j+1] - tau);
            a0 *= a0; a1 *= a1;
            row[j+0] = a0; row[j+1] = a1;
            s0 += a0; s1 += a1;
        }
        inv_sum = 1.0f / (s0 + s1);
    } else {
        // faithful general-alpha path (unused for this problem's alpha=1.5)
        const float inv = 1.0f / am1;
        float tau_m = tau_lo;
        float f_lo = -1.0f;
        #pragma unroll
        for (int j = 0; j < 64; ++j) f_lo += pgen(row[j] - tau_lo, inv);
        for (int it = 0; it < 30; ++it) {
            dm *= 0.5f;
            tau_m = tau_lo + dm;
            float f = -1.0f;
            #pragma unroll
            for (int j = 0; j < 64; ++j) f += pgen(row[j] - tau_m, inv);
            tau_lo = (f * f_lo >= 0.0f) ? tau_m : tau_lo;
        }
        float s = 0.0f;
        #pragma unroll
        for (int j = 0; j < 64; ++j) {
            const float pm = pgen(row[j] - tau_m, inv);
            row[j] = pm;
            s += pm;
        }
        inv_sum = 1.0f / s;
    }

    // ---- av: res[h][lane] = inv_sum * sum_j p[j] * v[h][j]  via fp16 dot2
    half2v p2[32];
    #pragma unroll
    for (int i = 0; i < 32; ++i) p2[i] = pk(row[2 * i], row[2 * i + 1]);

    float acc[8];
    #pragma unroll
    for (int h = 0; h < 8; ++h) {
        float a0 = 0.0f, a1 = 0.0f;
        #pragma unroll
        for (int jc = 0; jc < 8; ++jc) {
            union { half8 h8; half2v h2[4]; } u;
            u.h8 = *(const half8*)&v16[w][h * 32 + jc * 4];  // broadcast b128
            a0 = dot2(p2[jc * 4 + 0], u.h2[0], a0);
            a1 = dot2(p2[jc * 4 + 1], u.h2[1], a1);
            a0 = dot2(p2[jc * 4 + 2], u.h2[2], a0);
            a1 = dot2(p2[jc * 4 + 3], u.h2[3], a1);
        }
        acc[h] = a0 + a1;
    }
    float* rp = qb + (size_t)tok * HHE;   // res overwrites q (safe: own wave only)
    #pragma unroll
    for (int h = 0; h < 8; ++h) rp[h * 64 + lane] = acc[h] * inv_sum;
}

// ---------------------------------------------------------------------------
// Kernel 3: out = res @ Wu^T + bu   (M=16384, N=64, K=512)
// R5 version, unchanged (k-outer LDS GEMM, conflict-free). Held constant.
// ---------------------------------------------------------------------------
__global__ __launch_bounds__(256) void out_kernel(
    const float* __restrict__ resb, const float* __restrict__ Wu,
    const float* __restrict__ bu, float* __restrict__ out)
{
    __shared__ float rT[64 * 68];        // [kk][tok]  17.4 KB
    __shared__ float wT[64 * 68];        // [kk][m]    17.4 KB

    const int tid  = threadIdx.x;
    const int tok0 = blockIdx.x * 64;

    const int t    = tid >> 2;           // 0..63 (staging: token row / Wu row)
    const int kq2  = tid & 3;            // 0..3
    const int tokq = tid >> 4;           // 0..15 (compute: 4-token group)
    const int mq   = tid & 15;           // 0..15 (compute: 4-col group)

    float acc[4][4];
    #pragma unroll
    for (int a = 0; a < 4; ++a)
        #pragma unroll
        for (int b = 0; b < 4; ++b) acc[a][b] = 0.0f;

    const float4* rg = (const float4*)(resb + (size_t)(tok0 + t) * HHE);
    const float4* wg = (const float4*)(Wu   + (size_t)t * HHE);

    for (int kc = 0; kc < 8; ++kc) {
        // ---- stage res & Wu chunks transposed into LDS
        #pragma unroll
        for (int rep = 0; rep < 4; ++rep) {
            const int kq = rep * 4 + kq2;            // 0..15 within chunk
            const float4 rv = rg[kc * 16 + kq];
            rT[(kq * 4 + 0) * 68 + t] = rv.x;
            rT[(kq * 4 + 1) * 68 + t] = rv.y;
            rT[(kq * 4 + 2) * 68 + t] = rv.z;
            rT[(kq * 4 + 3) * 68 + t] = rv.w;
            const float4 wv = wg[kc * 16 + kq];
            wT[(kq * 4 + 0) * 68 + t] = wv.x;
            wT[(kq * 4 + 1) * 68 + t] = wv.y;
            wT[(kq * 4 + 2) * 68 + t] = wv.z;
            wT[(kq * 4 + 3) * 68 + t] = wv.w;
        }
        __syncthreads();

        // ---- compute: per kk, 2 x ds_read_b128 + 16 fma
        #pragma unroll 4
        for (int kk = 0; kk < 64; ++kk) {
            const float4 a4 = *(const float4*)&rT[kk * 68 + tokq * 4];
            const float4 b4 = *(const float4*)&wT[kk * 68 + mq * 4];
            const float ar[4] = {a4.x, a4.y, a4.z, a4.w};
            const float br[4] = {b4.x, b4.y, b4.z, b4.w};
            #pragma unroll
            for (int a = 0; a < 4; ++a)
                #pragma unroll
                for (int b = 0; b < 4; ++b)
                    acc[a][b] = fmaf(ar[a], br[b], acc[a][b]);
        }
        __syncthreads();                 // LDS reused next chunk
    }

    const float4 b4 = ((const float4*)bu)[mq];
    #pragma unroll
    for (int a = 0; a < 4; ++a) {
        float4 o;
        o.x = acc[a][0] + b4.x;
        o.y = acc[a][1] + b4.y;
        o.z = acc[a][2] + b4.z;
        o.w = acc[a][3] + b4.w;
        *(float4*)&out[(size_t)(tok0 + tokq * 4 + a) * 64 + mq * 4] = o;
    }
}

// ---------------------------------------------------------------------------
extern "C" void kernel_launch(void* const* d_in, const int* in_sizes, int n_in,
                              void* d_out, int out_size, void* d_ws, size_t ws_size,
                              hipStream_t stream)
{
    const float* x     = (const float*)d_in[0];
    const float* alpha = (const float*)d_in[1];
    const float* Wk    = (const float*)d_in[2];
    const float* bk    = (const float*)d_in[3];
    const float* Wq    = (const float*)d_in[4];
    const float* bq    = (const float*)d_in[5];
    const float* Wv    = (const float*)d_in[6];
    const float* bv    = (const float*)d_in[7];
    const float* Wu    = (const float*)d_in[8];
    const float* bu    = (const float*)d_in[9];
    float* out = (float*)d_out;

    float* ws = (float*)d_ws;
    float* qb = ws;                                  // res aliases q
    float* kb = ws + (size_t)NTOK * HHE;
    float* vb = ws + 2 * (size_t)NTOK * HHE;         // total 96 MB

    qkv_kernel<<<dim3(NTOK / 64, 4, 3), 256, 0, stream>>>(
        x, Wk, bk, Wq, bq, Wv, bv, qb, kb, vb);
    attn_kernel<<<NTOK / 4, 256, 0, stream>>>(qb, kb, vb, alpha);
    out_kernel<<<NTOK / 64, 256, 0, stream>>>(qb, Wu, bu, out);
}

// Round 12
// 212.146 us; speedup vs baseline: 1.0667x; 1.0667x over previous
//
#include <hip/hip_runtime.h>
#include <math.h>

// Problem constants (b=8, c=2048, e=64, h=8)
#define NTOK 16384
#define EDIM 64
#define HHE  512   // h*e

typedef _Float16 half8 __attribute__((ext_vector_type(8)));   // MFMA operand type
typedef __fp16   half2v __attribute__((ext_vector_type(2)));  // builtin V2h type
typedef float    floatx4 __attribute__((ext_vector_type(4)));

__device__ __forceinline__ half8 cvt8(const float4 a, const float4 b) {
    half8 h;
    h[0] = (_Float16)a.x; h[1] = (_Float16)a.y;
    h[2] = (_Float16)a.z; h[3] = (_Float16)a.w;
    h[4] = (_Float16)b.x; h[5] = (_Float16)b.y;
    h[6] = (_Float16)b.z; h[7] = (_Float16)b.w;
    return h;
}

// fp32 += half2 . half2 (v_dot2_f32_f16); float fallback if builtin missing
__device__ __forceinline__ float dot2(half2v a, half2v b, float c) {
#if __has_builtin(__builtin_amdgcn_fdot2)
    return __builtin_amdgcn_fdot2(a, b, c, false);
#else
    return fmaf((float)a[0], (float)b[0], fmaf((float)a[1], (float)b[1], c));
#endif
}
__device__ __forceinline__ half2v pk(float x, float y) {
    return __builtin_amdgcn_cvt_pkrtz(x, y);   // v_cvt_pkrtz_f16_f32 (V2h)
}
union h2u { half2v h; unsigned int u; };

// ---------------------------------------------------------------------------
// Kernel 1: q/k/v = x @ W^T + b  — MFMA, fp16 OUTPUT buffers.
// R11's swapped-operand layout kept (lane&15 = token, quad*4+reg = 4
// consecutive cols) so the fp16 epilogue is one 8 B packed store per tile.
// Rationale: qkv is HBM-write-locality-bound (~1.5 TB/s for both R10/R11
// store shapes); attn already rounds q/k/v to fp16 before use, so storing
// fp16 halves the write bytes with ZERO new rounding in the attn path.
// ---------------------------------------------------------------------------
__global__ __launch_bounds__(256) void qkv_kernel(
    const float* __restrict__ x,
    const float* __restrict__ Wk, const float* __restrict__ bk,
    const float* __restrict__ Wq, const float* __restrict__ bq,
    const float* __restrict__ Wv, const float* __restrict__ bv,
    unsigned short* __restrict__ qb, unsigned short* __restrict__ kb,
    unsigned short* __restrict__ vb)
{
    const int tid  = threadIdx.x;
    const int lane = tid & 63;
    const int wv   = tid >> 6;             // wave 0..3
    const int z    = blockIdx.z;

    const float* W; const float* bias; unsigned short* outp;
    if      (z == 0) { W = Wk; bias = bk; outp = kb; }
    else if (z == 1) { W = Wq; bias = bq; outp = qb; }
    else             { W = Wv; bias = bv; outp = vb; }

    const int tok0 = blockIdx.x * 64 + wv * 16;   // this wave's 16 tokens
    const int col0 = blockIdx.y * 128;            // this block's 128 cols

    const int m    = lane & 15;            // token (B row after swap)
    const int quad = lane >> 4;            // k-quad: k = quad*8 + j

    floatx4 acc[8];
    #pragma unroll
    for (int ct = 0; ct < 8; ++ct) acc[ct] = (floatx4){0.f, 0.f, 0.f, 0.f};

    const float* xrow = x + (size_t)(tok0 + m) * EDIM + quad * 8;

    #pragma unroll
    for (int kc = 0; kc < 2; ++kc) {       // K=64 in two 32-chunks
        const float4 xa = *(const float4*)(xrow + kc * 32);
        const float4 xb = *(const float4*)(xrow + kc * 32 + 4);
        const half8 bf = cvt8(xa, xb);     // x is the B operand
        #pragma unroll
        for (int ct = 0; ct < 8; ++ct) {
            const float* wrow =
                W + (size_t)(col0 + ct * 16 + m) * EDIM + quad * 8 + kc * 32;
            const float4 wa = *(const float4*)(wrow);
            const float4 wb = *(const float4*)(wrow + 4);
            const half8 af = cvt8(wa, wb); // W is the A operand
            acc[ct] = __builtin_amdgcn_mfma_f32_16x16x32_f16(af, bf, acc[ct], 0, 0, 0);
        }
    }

    // epilogue: D row = col (quad*4+reg), D col = tok (m). Pack 4 consecutive
    // cols + bias to fp16 -> one 8 B store per tile (write-combines to full
    // 128 B lines across the 4 adjacent ct quads).
    const int tok = tok0 + m;
    #pragma unroll
    for (int ct = 0; ct < 8; ++ct) {
        const int col = col0 + ct * 16 + quad * 4;
        const float4 b4 = *(const float4*)&bias[col];
        h2u p0, p1;
        p0.h = pk(acc[ct][0] + b4.x, acc[ct][1] + b4.y);
        p1.h = pk(acc[ct][2] + b4.z, acc[ct][3] + b4.w);
        uint2 st; st.x = p0.u; st.y = p1.u;
        *(uint2*)&outp[(size_t)tok * HHE + col] = st;
    }
}

// ---------------------------------------------------------------------------
// Kernel 2: per-token scores -> entmax_bisect -> att @ v  — fp16 in, fp16 LDS
// R10's proven structure (6-bisect + 3-guarded-Newton, barrier-free wave-
// private LDS). Inputs now fp16: q pairs assembled from ushort loads, k
// staged via uint packs, v staged via raw uint copies (no conversion at
// all). res written fp32 to its own buffer (no aliasing).
// ---------------------------------------------------------------------------
__device__ __forceinline__ float clamp01(float z) {
    return __builtin_amdgcn_fmed3f(z, 0.0f, 1.0f);   // v_med3_f32
}
__device__ __forceinline__ float pgen(float z, float inv) {
    return z > 0.0f ? exp2f(inv * log2f(fmaxf(z, 1e-30f))) : 0.0f;
}

__global__ __launch_bounds__(256) void attn_kernel(
    const unsigned short* __restrict__ qb, const unsigned short* __restrict__ kb,
    const unsigned short* __restrict__ vb, float* __restrict__ resb,
    const float* alpha_p)
{
    // per-wave private slices (1 KB each): no cross-wave sharing, no barrier
    __shared__ __align__(16) half2v kT[4][64 * 4];   // [w][j*4 + hpair]
    __shared__ __align__(16) half2v v16[4][8 * 32];  // [w][h*32 + jpair]

    const int lane = threadIdx.x & 63;
    const int w    = threadIdx.x >> 6;
    const int tok  = blockIdx.x * 4 + w;

    const float alpha = alpha_p[0];
    const float am1   = alpha - 1.0f;

    const unsigned short* __restrict__ qp = qb + (size_t)tok * HHE;
    const unsigned short* __restrict__ kp = kb + (size_t)tok * HHE;
    const unsigned short* __restrict__ vp = vb + (size_t)tok * HHE;

    // ---- q pairs: (q[2i][lane], q[2i+1][lane]) from ushort loads
    half2v q2[4];
    #pragma unroll
    for (int i = 0; i < 4; ++i) {
        h2u u;
        u.u = (unsigned int)qp[(2 * i) * 64 + lane]
            | ((unsigned int)qp[(2 * i + 1) * 64 + lane] << 16);
        q2[i] = u.h;
    }

    {   // k: lane j packs h-pairs, one b128 write
        unsigned int kk[4];
        #pragma unroll
        for (int i = 0; i < 4; ++i)
            kk[i] = (unsigned int)kp[(2 * i) * 64 + lane]
                  | ((unsigned int)kp[(2 * i + 1) * 64 + lane] << 16);
        uint4 st; st.x = kk[0]; st.y = kk[1]; st.z = kk[2]; st.w = kk[3];
        *(uint4*)&kT[w][lane * 4] = st;
    }
    {   // v: lane (jp = lane&31, hh = lane>>5) copies 4 h rows of j-pair jp
        const int jp = lane & 31;
        const int hh = lane >> 5;
        #pragma unroll
        for (int hi = 0; hi < 4; ++hi) {
            const int h = hh * 4 + hi;
            *(unsigned int*)&v16[w][h * 32 + jp] =
                *(const unsigned int*)&vp[h * 64 + 2 * jp];   // 4B-aligned
        }
    }
    // wave-private LDS: compiler's lgkmcnt ordering suffices (no barrier)

    // ---- dot row: row[j] = sum_h q[h][lane] * k[h][j]  (4 dot2 per j)
    float row[64];
    #pragma unroll
    for (int j = 0; j < 64; ++j) {
        union { half8 h8; half2v h2[4]; } u;
        u.h8 = *(const half8*)&kT[w][j * 4];        // broadcast b128
        float d = dot2(q2[0], u.h2[0], 0.0f);
        d = dot2(q2[1], u.h2[1], d);
        d = dot2(q2[2], u.h2[2], d);
        d = dot2(q2[3], u.h2[3], d);
        row[j] = d;
    }

    // Xa = dot/sqrt(e) * (alpha-1);  1/8 and am1 fold exactly (pow-of-2)
    const float scale = am1 * 0.125f;
    #pragma unroll
    for (int j = 0; j < 64; ++j) row[j] *= scale;

    float mx = row[0];
    #pragma unroll
    for (int j = 1; j < 64; ++j) mx = fmaxf(mx, row[j]);

    float tau_lo = mx - 1.0f;                         // _gp(1, alpha) = 1
    const float tau_hi = mx - exp2f(-6.0f * am1);     // (1/64)^am1
    float dm = tau_hi - tau_lo;
    float inv_sum;

    if (am1 == 0.5f) {
        // alpha = 1.5: p(z) = max(z,0)^2; z <= 1 always (tau >= mx-1).
        // 6 bisection steps, f >= 0 test (f_lo >= 0 provably; one-hot-safe).
        #pragma unroll
        for (int it = 0; it < 6; ++it) {
            dm *= 0.5f;
            const float tau_m = tau_lo + dm;
            float f0 = -1.0f, f1 = 0.0f, f2 = 0.0f, f3 = 0.0f;
            #pragma unroll
            for (int j = 0; j < 64; j += 4) {
                const float a0 = clamp01(row[j+0] - tau_m);
                const float a1 = clamp01(row[j+1] - tau_m);
                const float a2 = clamp01(row[j+2] - tau_m);
                const float a3 = clamp01(row[j+3] - tau_m);
                f0 = fmaf(a0, a0, f0); f1 = fmaf(a1, a1, f1);
                f2 = fmaf(a2, a2, f2); f3 = fmaf(a3, a3, f3);
            }
            const float f = (f0 + f1) + (f2 + f3);
            tau_lo = (f >= 0.0f) ? tau_m : tau_lo;
        }
        // 3 guarded Newton steps (tau += max(f,0)/(2s); never moves if f<0)
        float tau = tau_lo;
        #pragma unroll
        for (int it = 0; it < 3; ++it) {
            float f0 = -1.0f, f1 = 0.0f, f2 = 0.0f, f3 = 0.0f;
            float s0 = 0.0f, s1 = 0.0f, s2 = 0.0f, s3 = 0.0f;
            #pragma unroll
            for (int j = 0; j < 64; j += 4) {
                const float a0 = clamp01(row[j+0] - tau);
                const float a1 = clamp01(row[j+1] - tau);
                const float a2 = clamp01(row[j+2] - tau);
                const float a3 = clamp01(row[j+3] - tau);
                f0 = fmaf(a0, a0, f0); f1 = fmaf(a1, a1, f1);
                f2 = fmaf(a2, a2, f2); f3 = fmaf(a3, a3, f3);
                s0 += a0; s1 += a1; s2 += a2; s3 += a3;
            }
            const float f = (f0 + f1) + (f2 + f3);
            const float s = ((s0 + s1) + (s2 + s3)) + 1e-20f;  // s >= 1/8 anyway
            tau = tau + fmaxf(f, 0.0f) / (s + s);
        }
        // final p (unnormalized) + sum; normalization folded into av epilogue
        float s0 = 0.0f, s1 = 0.0f;
        #pragma unroll
        for (int j = 0; j < 64; j += 2) {
            float a0 = clamp01(row[j+0] - tau);
            float a1 = clamp01(row[j+1] - tau);
            a0 *= a0; a1 *= a1;
            row[j+0] = a0; row[j+1] = a1;
            s0 += a0; s1 += a1;
        }
        inv_sum = 1.0f / (s0 + s1);
    } else {
        // faithful general-alpha path (unused for this problem's alpha=1.5)
        const float inv = 1.0f / am1;
        float tau_m = tau_lo;
        float f_lo = -1.0f;
        #pragma unroll
        for (int j = 0; j < 64; ++j) f_lo += pgen(row[j] - tau_lo, inv);
        for (int it = 0; it < 30; ++it) {
            dm *= 0.5f;
            tau_m = tau_lo + dm;
            float f = -1.0f;
            #pragma unroll
            for (int j = 0; j < 64; ++j) f += pgen(row[j] - tau_m, inv);
            tau_lo = (f * f_lo >= 0.0f) ? tau_m : tau_lo;
        }
        float s = 0.0f;
        #pragma unroll
        for (int j = 0; j < 64; ++j) {
            const float pm = pgen(row[j] - tau_m, inv);
            row[j] = pm;
            s += pm;
        }
        inv_sum = 1.0f / s;
    }

    // ---- av: res[h][lane] = inv_sum * sum_j p[j] * v[h][j]  via fp16 dot2
    half2v p2[32];
    #pragma unroll
    for (int i = 0; i < 32; ++i) p2[i] = pk(row[2 * i], row[2 * i + 1]);

    float acc[8];
    #pragma unroll
    for (int h = 0; h < 8; ++h) {
        float a0 = 0.0f, a1 = 0.0f;
        #pragma unroll
        for (int jc = 0; jc < 8; ++jc) {
            union { half8 h8; half2v h2[4]; } u;
            u.h8 = *(const half8*)&v16[w][h * 32 + jc * 4];  // broadcast b128
            a0 = dot2(p2[jc * 4 + 0], u.h2[0], a0);
            a1 = dot2(p2[jc * 4 + 1], u.h2[1], a1);
            a0 = dot2(p2[jc * 4 + 2], u.h2[2], a0);
            a1 = dot2(p2[jc * 4 + 3], u.h2[3], a1);
        }
        acc[h] = a0 + a1;
    }
    float* rp = resb + (size_t)tok * HHE;
    #pragma unroll
    for (int h = 0; h < 8; ++h) rp[h * 64 + lane] = acc[h] * inv_sum;
}

// ---------------------------------------------------------------------------
// Kernel 3: out = res @ Wu^T + bu   (M=16384, N=64, K=512)
// R5 version, unchanged (k-outer LDS GEMM, conflict-free). Held constant.
// ---------------------------------------------------------------------------
__global__ __launch_bounds__(256) void out_kernel(
    const float* __restrict__ resb, const float* __restrict__ Wu,
    const float* __restrict__ bu, float* __restrict__ out)
{
    __shared__ float rT[64 * 68];        // [kk][tok]  17.4 KB
    __shared__ float wT[64 * 68];        // [kk][m]    17.4 KB

    const int tid  = threadIdx.x;
    const int tok0 = blockIdx.x * 64;

    const int t    = tid >> 2;           // 0..63 (staging: token row / Wu row)
    const int kq2  = tid & 3;            // 0..3
    const int tokq = tid >> 4;           // 0..15 (compute: 4-token group)
    const int mq   = tid & 15;           // 0..15 (compute: 4-col group)

    float acc[4][4];
    #pragma unroll
    for (int a = 0; a < 4; ++a)
        #pragma unroll
        for (int b = 0; b < 4; ++b) acc[a][b] = 0.0f;

    const float4* rg = (const float4*)(resb + (size_t)(tok0 + t) * HHE);
    const float4* wg = (const float4*)(Wu   + (size_t)t * HHE);

    for (int kc = 0; kc < 8; ++kc) {
        // ---- stage res & Wu chunks transposed into LDS
        #pragma unroll
        for (int rep = 0; rep < 4; ++rep) {
            const int kq = rep * 4 + kq2;            // 0..15 within chunk
            const float4 rv = rg[kc * 16 + kq];
            rT[(kq * 4 + 0) * 68 + t] = rv.x;
            rT[(kq * 4 + 1) * 68 + t] = rv.y;
            rT[(kq * 4 + 2) * 68 + t] = rv.z;
            rT[(kq * 4 + 3) * 68 + t] = rv.w;
            const float4 wv = wg[kc * 16 + kq];
            wT[(kq * 4 + 0) * 68 + t] = wv.x;
            wT[(kq * 4 + 1) * 68 + t] = wv.y;
            wT[(kq * 4 + 2) * 68 + t] = wv.z;
            wT[(kq * 4 + 3) * 68 + t] = wv.w;
        }
        __syncthreads();

        // ---- compute: per kk, 2 x ds_read_b128 + 16 fma
        #pragma unroll 4
        for (int kk = 0; kk < 64; ++kk) {
            const float4 a4 = *(const float4*)&rT[kk * 68 + tokq * 4];
            const float4 b4 = *(const float4*)&wT[kk * 68 + mq * 4];
            const float ar[4] = {a4.x, a4.y, a4.z, a4.w};
            const float br[4] = {b4.x, b4.y, b4.z, b4.w};
            #pragma unroll
            for (int a = 0; a < 4; ++a)
                #pragma unroll
                for (int b = 0; b < 4; ++b)
                    acc[a][b] = fmaf(ar[a], br[b], acc[a][b]);
        }
        __syncthreads();                 // LDS reused next chunk
    }

    const float4 b4 = ((const float4*)bu)[mq];
    #pragma unroll
    for (int a = 0; a < 4; ++a) {
        float4 o;
        o.x = acc[a][0] + b4.x;
        o.y = acc[a][1] + b4.y;
        o.z = acc[a][2] + b4.z;
        o.w = acc[a][3] + b4.w;
        *(float4*)&out[(size_t)(tok0 + tokq * 4 + a) * 64 + mq * 4] = o;
    }
}

// ---------------------------------------------------------------------------
extern "C" void kernel_launch(void* const* d_in, const int* in_sizes, int n_in,
                              void* d_out, int out_size, void* d_ws, size_t ws_size,
                              hipStream_t stream)
{
    const float* x     = (const float*)d_in[0];
    const float* alpha = (const float*)d_in[1];
    const float* Wk    = (const float*)d_in[2];
    const float* bk    = (const float*)d_in[3];
    const float* Wq    = (const float*)d_in[4];
    const float* bq    = (const float*)d_in[5];
    const float* Wv    = (const float*)d_in[6];
    const float* bv    = (const float*)d_in[7];
    const float* Wu    = (const float*)d_in[8];
    const float* bu    = (const float*)d_in[9];
    float* out = (float*)d_out;

    // workspace: q/k/v fp16 (16 MB each) + res fp32 (32 MB) = 80 MB
    unsigned short* qb = (unsigned short*)d_ws;
    unsigned short* kb = qb + (size_t)NTOK * HHE;
    unsigned short* vb = kb + (size_t)NTOK * HHE;
    float* resb = (float*)(vb + (size_t)NTOK * HHE);

    qkv_kernel<<<dim3(NTOK / 64, 4, 3), 256, 0, stream>>>(
        x, Wk, bk, Wq, bq, Wv, bv, qb, kb, vb);
    attn_kernel<<<NTOK / 4, 256, 0, stream>>>(qb, kb, vb, resb, alpha);
    out_kernel<<<NTOK / 64, 256, 0, stream>>>(resb, Wu, bu, out);
}

// Round 13
// 200.123 us; speedup vs baseline: 1.1308x; 1.0601x over previous
//
#include <hip/hip_runtime.h>
#include <math.h>

// Problem constants (b=8, c=2048, e=64, h=8)
#define NTOK 16384
#define EDIM 64
#define HHE  512   // h*e
#define TOKPAD 260 // half2 slots per token region (256 + 4 pad -> breaks bank alias)

typedef _Float16 half8 __attribute__((ext_vector_type(8)));   // MFMA operand type
typedef __fp16   half2v __attribute__((ext_vector_type(2)));  // builtin V2h type
typedef float    floatx4 __attribute__((ext_vector_type(4)));

__device__ __forceinline__ half8 cvt8(const float4 a, const float4 b) {
    half8 h;
    h[0] = (_Float16)a.x; h[1] = (_Float16)a.y;
    h[2] = (_Float16)a.z; h[3] = (_Float16)a.w;
    h[4] = (_Float16)b.x; h[5] = (_Float16)b.y;
    h[6] = (_Float16)b.z; h[7] = (_Float16)b.w;
    return h;
}

// fp32 += half2 . half2 (v_dot2_f32_f16); float fallback if builtin missing
__device__ __forceinline__ float dot2(half2v a, half2v b, float c) {
#if __has_builtin(__builtin_amdgcn_fdot2)
    return __builtin_amdgcn_fdot2(a, b, c, false);
#else
    return fmaf((float)a[0], (float)b[0], fmaf((float)a[1], (float)b[1], c));
#endif
}
__device__ __forceinline__ half2v pk(float x, float y) {
    return __builtin_amdgcn_cvt_pkrtz(x, y);   // v_cvt_pkrtz_f16_f32 (V2h)
}
union h2u { half2v h; unsigned int u; };

__device__ __forceinline__ float clamp01(float z) {
    return __builtin_amdgcn_fmed3f(z, 0.0f, 1.0f);   // v_med3_f32
}
__device__ __forceinline__ float pgen(float z, float inv) {
    return z > 0.0f ? exp2f(inv * log2f(fmaxf(z, 1e-30f))) : 0.0f;
}

// ---------------------------------------------------------------------------
// Kernel 1: FUSED qkv + entmax-attention. Block = 16 tokens, 4 waves.
// q/k/v never touch HBM (R10-R12 showed standalone qkv is stuck at ~66 µs on
// a gather/store latency floor regardless of byte count or store shape).
//
// Producer: 12 MFMA units (3 matrices x 4 col-tiles of 128), 3 per wave.
//  - x B-frags loaded once per wave (16-row gather, L1/L3-hot).
//  - q,k: W rows PERMUTED at load (g(n) = (n&7)*64 + (n>>3)) so each lane's
//    4 acc regs = 4 consecutive h at fixed j  -> one ds_write_b64 lands
//    directly in the [tok][j*4+hpair] layout the dot-loop broadcasts from.
//  - v: natural order -> lane's 4 regs = 4 consecutive j at fixed h -> one
//    ds_write_b64 into [tok][h*32+jpair].
//  - pk (cvt_pkrtz) at the same points as R12's epilogue => identical math.
// Consumer (after one barrier): R12's attn verbatim; each wave runs 4
// tokens serially (6 bisect + 3 guarded Newton, fp16 dot2 everywhere).
// ---------------------------------------------------------------------------
__global__ __launch_bounds__(256) void qkv_attn_kernel(
    const float* __restrict__ x,
    const float* __restrict__ Wk, const float* __restrict__ bk,
    const float* __restrict__ Wq, const float* __restrict__ bq,
    const float* __restrict__ Wv, const float* __restrict__ bv,
    float* __restrict__ resb, const float* alpha_p)
{
    __shared__ __align__(16) half2v qT[16 * TOKPAD];  // [tok][i*4 + hpair]
    __shared__ __align__(16) half2v kT[16 * TOKPAD];  // [tok][j*4 + hpair]
    __shared__ __align__(16) half2v vT[16 * TOKPAD];  // [tok][h*32 + jpair]

    const int tid  = threadIdx.x;
    const int lane = tid & 63;
    const int w    = tid >> 6;
    const int tok0 = blockIdx.x * 16;

    const int m    = lane & 15;            // token (B row)
    const int quad = lane >> 4;

    // ---- x B-fragments, shared by this wave's 3 units
    const float* xrow = x + (size_t)(tok0 + m) * EDIM + quad * 8;
    half8 bfr[2];
    bfr[0] = cvt8(*(const float4*)(xrow),      *(const float4*)(xrow + 4));
    bfr[1] = cvt8(*(const float4*)(xrow + 32), *(const float4*)(xrow + 36));

    // ---- producer: units w*3 .. w*3+2; unit = z*4 + ntile
    #pragma unroll
    for (int uu = 0; uu < 3; ++uu) {
        const int unit = w * 3 + uu;
        const int z    = unit >> 2;            // 0=k, 1=q, 2=v
        const int col0 = (unit & 3) * 128;
        const float* W    = (z == 0) ? Wk : (z == 1) ? Wq : Wv;
        const float* bias = (z == 0) ? bk : (z == 1) ? bq : bv;
        half2v* dstT      = (z == 0) ? kT : (z == 1) ? qT : vT;

        #pragma unroll
        for (int ct = 0; ct < 8; ++ct) {
            const int n = col0 + ct * 16 + m;
            // permuted W row for q/k; natural for v
            const int grow = (z < 2) ? ((n & 7) * 64 + (n >> 3)) : n;
            const float* wrow = W + (size_t)grow * EDIM + quad * 8;
            floatx4 acc = (floatx4){0.f, 0.f, 0.f, 0.f};
            #pragma unroll
            for (int kc = 0; kc < 2; ++kc) {
                const half8 af = cvt8(*(const float4*)(wrow + kc * 32),
                                      *(const float4*)(wrow + kc * 32 + 4));
                acc = __builtin_amdgcn_mfma_f32_16x16x32_f16(af, bfr[kc], acc, 0, 0, 0);
            }
            // lane's 4 regs = D rows quad*4+0..3, D col = m (token)
            h2u p0, p1;
            if (z < 2) {
                // output rows g(n'): h = 4*(quad&1)+reg, j = col0/8+ct*2+(quad>>1)
                const int hbase = 4 * (quad & 1);
                const int j     = (col0 >> 3) + ct * 2 + (quad >> 1);
                float o0 = acc[0] + bias[(hbase + 0) * 64 + j];
                float o1 = acc[1] + bias[(hbase + 1) * 64 + j];
                float o2 = acc[2] + bias[(hbase + 2) * 64 + j];
                float o3 = acc[3] + bias[(hbase + 3) * 64 + j];
                p0.h = pk(o0, o1);                 // h-pair 2*(quad&1)
                p1.h = pk(o2, o3);                 // h-pair 2*(quad&1)+1
                uint2 st; st.x = p0.u; st.y = p1.u;
                *(uint2*)&dstT[m * TOKPAD + j * 4 + 2 * (quad & 1)] = st;
            } else {
                // natural: cols nn..nn+3 = v[h][jj..jj+3]
                const int nn = col0 + ct * 16 + quad * 4;
                const int h  = nn >> 6;
                const int jj = nn & 63;
                const float4 b4 = *(const float4*)&bias[nn];
                p0.h = pk(acc[0] + b4.x, acc[1] + b4.y);
                p1.h = pk(acc[2] + b4.z, acc[3] + b4.w);
                uint2 st; st.x = p0.u; st.y = p1.u;
                *(uint2*)&dstT[m * TOKPAD + h * 32 + (jj >> 1)] = st;
            }
        }
    }
    __syncthreads();   // producer (all waves write all 16 tokens) -> consumer

    const float alpha = alpha_p[0];
    const float am1   = alpha - 1.0f;

    // ---- consumer: each wave runs 4 tokens serially
    for (int i = 0; i < 4; ++i) {
        const int t   = w * 4 + i;
        const int tok = tok0 + t;

        union { half8 h8; half2v h2[4]; } uq;
        uq.h8 = *(const half8*)&qT[t * TOKPAD + lane * 4];

        // dot row: row[j] = sum_h q[h][lane] * k[h][j]  (4 dot2 per j)
        float row[64];
        #pragma unroll
        for (int j = 0; j < 64; ++j) {
            union { half8 h8; half2v h2[4]; } u;
            u.h8 = *(const half8*)&kT[t * TOKPAD + j * 4];   // broadcast b128
            float d = dot2(uq.h2[0], u.h2[0], 0.0f);
            d = dot2(uq.h2[1], u.h2[1], d);
            d = dot2(uq.h2[2], u.h2[2], d);
            d = dot2(uq.h2[3], u.h2[3], d);
            row[j] = d;
        }

        // Xa = dot/sqrt(e) * (alpha-1);  1/8 and am1 fold exactly (pow-of-2)
        const float scale = am1 * 0.125f;
        #pragma unroll
        for (int j = 0; j < 64; ++j) row[j] *= scale;

        float mx = row[0];
        #pragma unroll
        for (int j = 1; j < 64; ++j) mx = fmaxf(mx, row[j]);

        float tau_lo = mx - 1.0f;                         // _gp(1, alpha) = 1
        const float tau_hi = mx - exp2f(-6.0f * am1);     // (1/64)^am1
        float dm = tau_hi - tau_lo;
        float inv_sum;

        if (am1 == 0.5f) {
            // 6 bisection steps, f >= 0 test (f_lo >= 0 provably; one-hot-safe)
            #pragma unroll
            for (int it = 0; it < 6; ++it) {
                dm *= 0.5f;
                const float tau_m = tau_lo + dm;
                float f0 = -1.0f, f1 = 0.0f, f2 = 0.0f, f3 = 0.0f;
                #pragma unroll
                for (int j = 0; j < 64; j += 4) {
                    const float a0 = clamp01(row[j+0] - tau_m);
                    const float a1 = clamp01(row[j+1] - tau_m);
                    const float a2 = clamp01(row[j+2] - tau_m);
                    const float a3 = clamp01(row[j+3] - tau_m);
                    f0 = fmaf(a0, a0, f0); f1 = fmaf(a1, a1, f1);
                    f2 = fmaf(a2, a2, f2); f3 = fmaf(a3, a3, f3);
                }
                const float f = (f0 + f1) + (f2 + f3);
                tau_lo = (f >= 0.0f) ? tau_m : tau_lo;
            }
            // 3 guarded Newton steps (tau += max(f,0)/(2s); never moves if f<0)
            float tau = tau_lo;
            #pragma unroll
            for (int it = 0; it < 3; ++it) {
                float f0 = -1.0f, f1 = 0.0f, f2 = 0.0f, f3 = 0.0f;
                float s0 = 0.0f, s1 = 0.0f, s2 = 0.0f, s3 = 0.0f;
                #pragma unroll
                for (int j = 0; j < 64; j += 4) {
                    const float a0 = clamp01(row[j+0] - tau);
                    const float a1 = clamp01(row[j+1] - tau);
                    const float a2 = clamp01(row[j+2] - tau);
                    const float a3 = clamp01(row[j+3] - tau);
                    f0 = fmaf(a0, a0, f0); f1 = fmaf(a1, a1, f1);
                    f2 = fmaf(a2, a2, f2); f3 = fmaf(a3, a3, f3);
                    s0 += a0; s1 += a1; s2 += a2; s3 += a3;
                }
                const float f = (f0 + f1) + (f2 + f3);
                const float s = ((s0 + s1) + (s2 + s3)) + 1e-20f;  // s >= 1/8
                tau = tau + fmaxf(f, 0.0f) / (s + s);
            }
            // final p (unnormalized) + sum; normalization folded into av
            float s0 = 0.0f, s1 = 0.0f;
            #pragma unroll
            for (int j = 0; j < 64; j += 2) {
                float a0 = clamp01(row[j+0] - tau);
                float a1 = clamp01(row[j+1] - tau);
                a0 *= a0; a1 *= a1;
                row[j+0] = a0; row[j+1] = a1;
                s0 += a0; s1 += a1;
            }
            inv_sum = 1.0f / (s0 + s1);
        } else {
            // faithful general-alpha path (unused for this problem's alpha=1.5)
            const float inv = 1.0f / am1;
            float tau_m = tau_lo;
            float f_lo = -1.0f;
            #pragma unroll
            for (int j = 0; j < 64; ++j) f_lo += pgen(row[j] - tau_lo, inv);
            for (int it = 0; it < 30; ++it) {
                dm *= 0.5f;
                tau_m = tau_lo + dm;
                float f = -1.0f;
                #pragma unroll
                for (int j = 0; j < 64; ++j) f += pgen(row[j] - tau_m, inv);
                tau_lo = (f * f_lo >= 0.0f) ? tau_m : tau_lo;
            }
            float s = 0.0f;
            #pragma unroll
            for (int j = 0; j < 64; ++j) {
                const float pm = pgen(row[j] - tau_m, inv);
                row[j] = pm;
                s += pm;
            }
            inv_sum = 1.0f / s;
        }

        // av: res[h][lane] = inv_sum * sum_j p[j] * v[h][j]  via fp16 dot2
        half2v p2[32];
        #pragma unroll
        for (int ii = 0; ii < 32; ++ii) p2[ii] = pk(row[2 * ii], row[2 * ii + 1]);

        float acc[8];
        #pragma unroll
        for (int h = 0; h < 8; ++h) {
            float a0 = 0.0f, a1 = 0.0f;
            #pragma unroll
            for (int jc = 0; jc < 8; ++jc) {
                union { half8 h8; half2v h2[4]; } u;
                u.h8 = *(const half8*)&vT[t * TOKPAD + h * 32 + jc * 4];
                a0 = dot2(p2[jc * 4 + 0], u.h2[0], a0);
                a1 = dot2(p2[jc * 4 + 1], u.h2[1], a1);
                a0 = dot2(p2[jc * 4 + 2], u.h2[2], a0);
                a1 = dot2(p2[jc * 4 + 3], u.h2[3], a1);
            }
            acc[h] = a0 + a1;
        }
        float* rp = resb + (size_t)tok * HHE;
        #pragma unroll
        for (int h = 0; h < 8; ++h) rp[h * 64 + lane] = acc[h] * inv_sum;
    }
}

// ---------------------------------------------------------------------------
// Kernel 2: out = res @ Wu^T + bu   (M=16384, N=64, K=512)
// R5 version, unchanged (k-outer LDS GEMM, conflict-free). Held constant.
// ---------------------------------------------------------------------------
__global__ __launch_bounds__(256) void out_kernel(
    const float* __restrict__ resb, const float* __restrict__ Wu,
    const float* __restrict__ bu, float* __restrict__ out)
{
    __shared__ float rT[64 * 68];        // [kk][tok]  17.4 KB
    __shared__ float wT[64 * 68];        // [kk][m]    17.4 KB

    const int tid  = threadIdx.x;
    const int tok0 = blockIdx.x * 64;

    const int t    = tid >> 2;           // 0..63 (staging: token row / Wu row)
    const int kq2  = tid & 3;            // 0..3
    const int tokq = tid >> 4;           // 0..15 (compute: 4-token group)
    const int mq   = tid & 15;           // 0..15 (compute: 4-col group)

    float acc[4][4];
    #pragma unroll
    for (int a = 0; a < 4; ++a)
        #pragma unroll
        for (int b = 0; b < 4; ++b) acc[a][b] = 0.0f;

    const float4* rg = (const float4*)(resb + (size_t)(tok0 + t) * HHE);
    const float4* wg = (const float4*)(Wu   + (size_t)t * HHE);

    for (int kc = 0; kc < 8; ++kc) {
        // ---- stage res & Wu chunks transposed into LDS
        #pragma unroll
        for (int rep = 0; rep < 4; ++rep) {
            const int kq = rep * 4 + kq2;            // 0..15 within chunk
            const float4 rv = rg[kc * 16 + kq];
            rT[(kq * 4 + 0) * 68 + t] = rv.x;
            rT[(kq * 4 + 1) * 68 + t] = rv.y;
            rT[(kq * 4 + 2) * 68 + t] = rv.z;
            rT[(kq * 4 + 3) * 68 + t] = rv.w;
            const float4 wv = wg[kc * 16 + kq];
            wT[(kq * 4 + 0) * 68 + t] = wv.x;
            wT[(kq * 4 + 1) * 68 + t] = wv.y;
            wT[(kq * 4 + 2) * 68 + t] = wv.z;
            wT[(kq * 4 + 3) * 68 + t] = wv.w;
        }
        __syncthreads();

        // ---- compute: per kk, 2 x ds_read_b128 + 16 fma
        #pragma unroll 4
        for (int kk = 0; kk < 64; ++kk) {
            const float4 a4 = *(const float4*)&rT[kk * 68 + tokq * 4];
            const float4 b4 = *(const float4*)&wT[kk * 68 + mq * 4];
            const float ar[4] = {a4.x, a4.y, a4.z, a4.w};
            const float br[4] = {b4.x, b4.y, b4.z, b4.w};
            #pragma unroll
            for (int a = 0; a < 4; ++a)
                #pragma unroll
                for (int b = 0; b < 4; ++b)
                    acc[a][b] = fmaf(ar[a], br[b], acc[a][b]);
        }
        __syncthreads();                 // LDS reused next chunk
    }

    const float4 b4 = ((const float4*)bu)[mq];
    #pragma unroll
    for (int a = 0; a < 4; ++a) {
        float4 o;
        o.x = acc[a][0] + b4.x;
        o.y = acc[a][1] + b4.y;
        o.z = acc[a][2] + b4.z;
        o.w = acc[a][3] + b4.w;
        *(float4*)&out[(size_t)(tok0 + tokq * 4 + a) * 64 + mq * 4] = o;
    }
}

// ---------------------------------------------------------------------------
extern "C" void kernel_launch(void* const* d_in, const int* in_sizes, int n_in,
                              void* d_out, int out_size, void* d_ws, size_t ws_size,
                              hipStream_t stream)
{
    const float* x     = (const float*)d_in[0];
    const float* alpha = (const float*)d_in[1];
    const float* Wk    = (const float*)d_in[2];
    const float* bk    = (const float*)d_in[3];
    const float* Wq    = (const float*)d_in[4];
    const float* bq    = (const float*)d_in[5];
    const float* Wv    = (const float*)d_in[6];
    const float* bv    = (const float*)d_in[7];
    const float* Wu    = (const float*)d_in[8];
    const float* bu    = (const float*)d_in[9];
    float* out = (float*)d_out;

    float* resb = (float*)d_ws;    // res fp32, 32 MB — only intermediate left

    qkv_attn_kernel<<<NTOK / 16, 256, 0, stream>>>(
        x, Wk, bk, Wq, bq, Wv, bv, resb, alpha);
    out_kernel<<<NTOK / 64, 256, 0, stream>>>(resb, Wu, bu, out);
}

// Round 14
// 193.930 us; speedup vs baseline: 1.1669x; 1.0319x over previous
//
#include <hip/hip_runtime.h>
#include <math.h>

// Problem constants (b=8, c=2048, e=64, h=8)
#define NTOK 16384
#define EDIM 64
#define HHE  512   // h*e
#define TOKPAD 260 // half2 slots per token region (256 + 4 pad -> breaks bank alias)

typedef _Float16 half8 __attribute__((ext_vector_type(8)));   // MFMA operand type
typedef __fp16   half2v __attribute__((ext_vector_type(2)));  // builtin V2h type
typedef float    floatx4 __attribute__((ext_vector_type(4)));

__device__ __forceinline__ half8 cvt8(const float4 a, const float4 b) {
    half8 h;
    h[0] = (_Float16)a.x; h[1] = (_Float16)a.y;
    h[2] = (_Float16)a.z; h[3] = (_Float16)a.w;
    h[4] = (_Float16)b.x; h[5] = (_Float16)b.y;
    h[6] = (_Float16)b.z; h[7] = (_Float16)b.w;
    return h;
}

// fp32 += half2 . half2 (v_dot2_f32_f16); float fallback if builtin missing
__device__ __forceinline__ float dot2(half2v a, half2v b, float c) {
#if __has_builtin(__builtin_amdgcn_fdot2)
    return __builtin_amdgcn_fdot2(a, b, c, false);
#else
    return fmaf((float)a[0], (float)b[0], fmaf((float)a[1], (float)b[1], c));
#endif
}
__device__ __forceinline__ half2v pk(float x, float y) {
    return __builtin_amdgcn_cvt_pkrtz(x, y);   // v_cvt_pkrtz_f16_f32 (V2h)
}
union h2u { half2v h; unsigned int u; };

__device__ __forceinline__ float clamp01(float z) {
    return __builtin_amdgcn_fmed3f(z, 0.0f, 1.0f);   // v_med3_f32
}
__device__ __forceinline__ float pgen(float z, float inv) {
    return z > 0.0f ? exp2f(inv * log2f(fmaxf(z, 1e-30f))) : 0.0f;
}

// ---------------------------------------------------------------------------
// Kernel 1: FUSED qkv + entmax-attention. Block = 16 tokens, 4 waves.
// R13 version; ONLY change: res stored fp16 (feeds out's MFMA B-operand
// directly; WRITE 32 -> 16 MB; <=1e-3 rel rounding on res).
// ---------------------------------------------------------------------------
__global__ __launch_bounds__(256) void qkv_attn_kernel(
    const float* __restrict__ x,
    const float* __restrict__ Wk, const float* __restrict__ bk,
    const float* __restrict__ Wq, const float* __restrict__ bq,
    const float* __restrict__ Wv, const float* __restrict__ bv,
    __fp16* __restrict__ resb, const float* alpha_p)
{
    __shared__ __align__(16) half2v qT[16 * TOKPAD];  // [tok][i*4 + hpair]
    __shared__ __align__(16) half2v kT[16 * TOKPAD];  // [tok][j*4 + hpair]
    __shared__ __align__(16) half2v vT[16 * TOKPAD];  // [tok][h*32 + jpair]

    const int tid  = threadIdx.x;
    const int lane = tid & 63;
    const int w    = tid >> 6;
    const int tok0 = blockIdx.x * 16;

    const int m    = lane & 15;            // token (B row)
    const int quad = lane >> 4;

    // ---- x B-fragments, shared by this wave's 3 units
    const float* xrow = x + (size_t)(tok0 + m) * EDIM + quad * 8;
    half8 bfr[2];
    bfr[0] = cvt8(*(const float4*)(xrow),      *(const float4*)(xrow + 4));
    bfr[1] = cvt8(*(const float4*)(xrow + 32), *(const float4*)(xrow + 36));

    // ---- producer: units w*3 .. w*3+2; unit = z*4 + ntile
    #pragma unroll
    for (int uu = 0; uu < 3; ++uu) {
        const int unit = w * 3 + uu;
        const int z    = unit >> 2;            // 0=k, 1=q, 2=v
        const int col0 = (unit & 3) * 128;
        const float* W    = (z == 0) ? Wk : (z == 1) ? Wq : Wv;
        const float* bias = (z == 0) ? bk : (z == 1) ? bq : bv;
        half2v* dstT      = (z == 0) ? kT : (z == 1) ? qT : vT;

        #pragma unroll
        for (int ct = 0; ct < 8; ++ct) {
            const int n = col0 + ct * 16 + m;
            // permuted W row for q/k; natural for v
            const int grow = (z < 2) ? ((n & 7) * 64 + (n >> 3)) : n;
            const float* wrow = W + (size_t)grow * EDIM + quad * 8;
            floatx4 acc = (floatx4){0.f, 0.f, 0.f, 0.f};
            #pragma unroll
            for (int kc = 0; kc < 2; ++kc) {
                const half8 af = cvt8(*(const float4*)(wrow + kc * 32),
                                      *(const float4*)(wrow + kc * 32 + 4));
                acc = __builtin_amdgcn_mfma_f32_16x16x32_f16(af, bfr[kc], acc, 0, 0, 0);
            }
            // lane's 4 regs = D rows quad*4+0..3, D col = m (token)
            h2u p0, p1;
            if (z < 2) {
                // output rows g(n'): h = 4*(quad&1)+reg, j = col0/8+ct*2+(quad>>1)
                const int hbase = 4 * (quad & 1);
                const int j     = (col0 >> 3) + ct * 2 + (quad >> 1);
                float o0 = acc[0] + bias[(hbase + 0) * 64 + j];
                float o1 = acc[1] + bias[(hbase + 1) * 64 + j];
                float o2 = acc[2] + bias[(hbase + 2) * 64 + j];
                float o3 = acc[3] + bias[(hbase + 3) * 64 + j];
                p0.h = pk(o0, o1);                 // h-pair 2*(quad&1)
                p1.h = pk(o2, o3);                 // h-pair 2*(quad&1)+1
                uint2 st; st.x = p0.u; st.y = p1.u;
                *(uint2*)&dstT[m * TOKPAD + j * 4 + 2 * (quad & 1)] = st;
            } else {
                // natural: cols nn..nn+3 = v[h][jj..jj+3]
                const int nn = col0 + ct * 16 + quad * 4;
                const int h  = nn >> 6;
                const int jj = nn & 63;
                const float4 b4 = *(const float4*)&bias[nn];
                p0.h = pk(acc[0] + b4.x, acc[1] + b4.y);
                p1.h = pk(acc[2] + b4.z, acc[3] + b4.w);
                uint2 st; st.x = p0.u; st.y = p1.u;
                *(uint2*)&dstT[m * TOKPAD + h * 32 + (jj >> 1)] = st;
            }
        }
    }
    __syncthreads();   // producer (all waves write all 16 tokens) -> consumer

    const float alpha = alpha_p[0];
    const float am1   = alpha - 1.0f;

    // ---- consumer: each wave runs 4 tokens serially
    for (int i = 0; i < 4; ++i) {
        const int t   = w * 4 + i;
        const int tok = tok0 + t;

        union { half8 h8; half2v h2[4]; } uq;
        uq.h8 = *(const half8*)&qT[t * TOKPAD + lane * 4];

        // dot row: row[j] = sum_h q[h][lane] * k[h][j]  (4 dot2 per j)
        float row[64];
        #pragma unroll
        for (int j = 0; j < 64; ++j) {
            union { half8 h8; half2v h2[4]; } u;
            u.h8 = *(const half8*)&kT[t * TOKPAD + j * 4];   // broadcast b128
            float d = dot2(uq.h2[0], u.h2[0], 0.0f);
            d = dot2(uq.h2[1], u.h2[1], d);
            d = dot2(uq.h2[2], u.h2[2], d);
            d = dot2(uq.h2[3], u.h2[3], d);
            row[j] = d;
        }

        // Xa = dot/sqrt(e) * (alpha-1);  1/8 and am1 fold exactly (pow-of-2)
        const float scale = am1 * 0.125f;
        #pragma unroll
        for (int j = 0; j < 64; ++j) row[j] *= scale;

        float mx = row[0];
        #pragma unroll
        for (int j = 1; j < 64; ++j) mx = fmaxf(mx, row[j]);

        float tau_lo = mx - 1.0f;                         // _gp(1, alpha) = 1
        const float tau_hi = mx - exp2f(-6.0f * am1);     // (1/64)^am1
        float dm = tau_hi - tau_lo;
        float inv_sum;

        if (am1 == 0.5f) {
            // 6 bisection steps, f >= 0 test (f_lo >= 0 provably; one-hot-safe)
            #pragma unroll
            for (int it = 0; it < 6; ++it) {
                dm *= 0.5f;
                const float tau_m = tau_lo + dm;
                float f0 = -1.0f, f1 = 0.0f, f2 = 0.0f, f3 = 0.0f;
                #pragma unroll
                for (int j = 0; j < 64; j += 4) {
                    const float a0 = clamp01(row[j+0] - tau_m);
                    const float a1 = clamp01(row[j+1] - tau_m);
                    const float a2 = clamp01(row[j+2] - tau_m);
                    const float a3 = clamp01(row[j+3] - tau_m);
                    f0 = fmaf(a0, a0, f0); f1 = fmaf(a1, a1, f1);
                    f2 = fmaf(a2, a2, f2); f3 = fmaf(a3, a3, f3);
                }
                const float f = (f0 + f1) + (f2 + f3);
                tau_lo = (f >= 0.0f) ? tau_m : tau_lo;
            }
            // 3 guarded Newton steps (tau += max(f,0)/(2s); never moves if f<0)
            float tau = tau_lo;
            #pragma unroll
            for (int it = 0; it < 3; ++it) {
                float f0 = -1.0f, f1 = 0.0f, f2 = 0.0f, f3 = 0.0f;
                float s0 = 0.0f, s1 = 0.0f, s2 = 0.0f, s3 = 0.0f;
                #pragma unroll
                for (int j = 0; j < 64; j += 4) {
                    const float a0 = clamp01(row[j+0] - tau);
                    const float a1 = clamp01(row[j+1] - tau);
                    const float a2 = clamp01(row[j+2] - tau);
                    const float a3 = clamp01(row[j+3] - tau);
                    f0 = fmaf(a0, a0, f0); f1 = fmaf(a1, a1, f1);
                    f2 = fmaf(a2, a2, f2); f3 = fmaf(a3, a3, f3);
                    s0 += a0; s1 += a1; s2 += a2; s3 += a3;
                }
                const float f = (f0 + f1) + (f2 + f3);
                const float s = ((s0 + s1) + (s2 + s3)) + 1e-20f;  // s >= 1/8
                tau = tau + fmaxf(f, 0.0f) / (s + s);
            }
            // final p (unnormalized) + sum; normalization folded into av
            float s0 = 0.0f, s1 = 0.0f;
            #pragma unroll
            for (int j = 0; j < 64; j += 2) {
                float a0 = clamp01(row[j+0] - tau);
                float a1 = clamp01(row[j+1] - tau);
                a0 *= a0; a1 *= a1;
                row[j+0] = a0; row[j+1] = a1;
                s0 += a0; s1 += a1;
            }
            inv_sum = 1.0f / (s0 + s1);
        } else {
            // faithful general-alpha path (unused for this problem's alpha=1.5)
            const float inv = 1.0f / am1;
            float tau_m = tau_lo;
            float f_lo = -1.0f;
            #pragma unroll
            for (int j = 0; j < 64; ++j) f_lo += pgen(row[j] - tau_lo, inv);
            for (int it = 0; it < 30; ++it) {
                dm *= 0.5f;
                tau_m = tau_lo + dm;
                float f = -1.0f;
                #pragma unroll
                for (int j = 0; j < 64; ++j) f += pgen(row[j] - tau_m, inv);
                tau_lo = (f * f_lo >= 0.0f) ? tau_m : tau_lo;
            }
            float s = 0.0f;
            #pragma unroll
            for (int j = 0; j < 64; ++j) {
                const float pm = pgen(row[j] - tau_m, inv);
                row[j] = pm;
                s += pm;
            }
            inv_sum = 1.0f / s;
        }

        // av: res[h][lane] = inv_sum * sum_j p[j] * v[h][j]  via fp16 dot2
        half2v p2[32];
        #pragma unroll
        for (int ii = 0; ii < 32; ++ii) p2[ii] = pk(row[2 * ii], row[2 * ii + 1]);

        float acc[8];
        #pragma unroll
        for (int h = 0; h < 8; ++h) {
            float a0 = 0.0f, a1 = 0.0f;
            #pragma unroll
            for (int jc = 0; jc < 8; ++jc) {
                union { half8 h8; half2v h2[4]; } u;
                u.h8 = *(const half8*)&vT[t * TOKPAD + h * 32 + jc * 4];
                a0 = dot2(p2[jc * 4 + 0], u.h2[0], a0);
                a1 = dot2(p2[jc * 4 + 1], u.h2[1], a1);
                a0 = dot2(p2[jc * 4 + 2], u.h2[2], a0);
                a1 = dot2(p2[jc * 4 + 3], u.h2[3], a1);
            }
            acc[h] = a0 + a1;
        }
        // res stored fp16 (per-h segments are 128 B contiguous -> coalesced)
        __fp16* rp = resb + (size_t)tok * HHE;
        #pragma unroll
        for (int h = 0; h < 8; ++h) rp[h * 64 + lane] = (__fp16)(acc[h] * inv_sum);
    }
}

// ---------------------------------------------------------------------------
// Kernel 2: out = res @ Wu^T + bu  (M=16384, N=64, K=512) — MFMA REWRITE
// Zero LDS, zero barriers (R13 showed the LDS version was a 1-block/CU
// DS-latency serial chain at ~60 µs for 7 µs of math). Proven R11/R12
// swapped-operand mapping: af = Wu-frag, bf = res-frag (fp16, direct half8
// loads), D col = token (lane&15), D rows = 4 consecutive out-cols ->
// one float4 store per tile. Wave = 16 tok x 32 cols (2 ct tiles) so the
// grid is 2048 waves = 8 waves/CU for gather-latency hiding.
// ---------------------------------------------------------------------------
__global__ __launch_bounds__(256) void out_kernel(
    const __fp16* __restrict__ resh, const float* __restrict__ Wu,
    const float* __restrict__ bu, float* __restrict__ out)
{
    const int tid  = threadIdx.x;
    const int lane = tid & 63;
    const int w    = tid >> 6;
    const int m    = lane & 15;
    const int quad = lane >> 4;

    const int tok0 = blockIdx.x * 32 + (w >> 1) * 16;  // 32 tok/block, 16/wave
    const int ctb  = (w & 1) * 2;                      // ct tiles ctb, ctb+1

    floatx4 acc[2];
    acc[0] = (floatx4){0.f, 0.f, 0.f, 0.f};
    acc[1] = (floatx4){0.f, 0.f, 0.f, 0.f};

    const __fp16* rrow = resh + (size_t)(tok0 + m) * HHE + quad * 8;

    #pragma unroll
    for (int kc = 0; kc < 16; ++kc) {                  // K=512 in 32-chunks
        const half8 bf = *(const half8*)(rrow + kc * 32);   // direct fp16 load
        #pragma unroll
        for (int c = 0; c < 2; ++c) {
            const int n = (ctb + c) * 16 + m;          // out column (Wu row)
            const float* wrow = Wu + (size_t)n * HHE + kc * 32 + quad * 8;
            const half8 af = cvt8(*(const float4*)(wrow),
                                  *(const float4*)(wrow + 4));
            acc[c] = __builtin_amdgcn_mfma_f32_16x16x32_f16(af, bf, acc[c], 0, 0, 0);
        }
    }

    const int tok = tok0 + m;
    #pragma unroll
    for (int c = 0; c < 2; ++c) {
        const int col = (ctb + c) * 16 + quad * 4;     // 4 consecutive out cols
        const float4 b4 = *(const float4*)&bu[col];
        float4 o;
        o.x = acc[c][0] + b4.x;
        o.y = acc[c][1] + b4.y;
        o.z = acc[c][2] + b4.z;
        o.w = acc[c][3] + b4.w;
        *(float4*)&out[(size_t)tok * 64 + col] = o;
    }
}

// ---------------------------------------------------------------------------
extern "C" void kernel_launch(void* const* d_in, const int* in_sizes, int n_in,
                              void* d_out, int out_size, void* d_ws, size_t ws_size,
                              hipStream_t stream)
{
    const float* x     = (const float*)d_in[0];
    const float* alpha = (const float*)d_in[1];
    const float* Wk    = (const float*)d_in[2];
    const float* bk    = (const float*)d_in[3];
    const float* Wq    = (const float*)d_in[4];
    const float* bq    = (const float*)d_in[5];
    const float* Wv    = (const float*)d_in[6];
    const float* bv    = (const float*)d_in[7];
    const float* Wu    = (const float*)d_in[8];
    const float* bu    = (const float*)d_in[9];
    float* out = (float*)d_out;

    __fp16* resb = (__fp16*)d_ws;   // res fp16, 16 MB — only intermediate left

    qkv_attn_kernel<<<NTOK / 16, 256, 0, stream>>>(
        x, Wk, bk, Wq, bq, Wv, bv, resb, alpha);
    out_kernel<<<NTOK / 32, 256, 0, stream>>>(resb, Wu, bu, out);
}